// Round 3
// baseline (358.126 us; speedup 1.0000x reference)
//
#include <hip/hip_runtime.h>
#include <math.h>

// MADE autoregressive sampler, incremental-by-degree, v15.
// B=8192, D=64, CTX=256, H=512. Units sorted by degree (mh = h%63+1).
// v15: occupancy attack. v14 evidence: VALUBusy fell 48.6->44.6 with duration
// pinned at ~185us => latency-bound, and OccupancyPercent=37.5% = exactly
// 12/32 waves/CU. Restructure: 512-thread blocks, ONE unit per thread (q=t),
// still Rn=8 rows/block -> 1024 blocks x 8 waves, 4 blocks/CU = 32 waves/CU
// (100%). Total FLOPs / weight traffic / barriers-per-block unchanged; per-
// thread state halves so the 64-VGPR clamp for 8 waves/SIMD fits.
// Phase-local load placement (minimal live ranges, TLP covers latency):
//   c2 (FA weight, slots 8-11) issued pre-bar1 (no z-dep: hides under barrier)
//   c0/c1 (MID weights) after bar1 (hides under FA + bar2 wait)
//   Woq + h2g row read after bar3 (exposed ~200cy, covered by 8 waves/SIMD)
// Raw lgkm-only barriers kept from v14 (global loads fly across barriers).

typedef float f2 __attribute__((ext_vector_type(2)));

#define Bn 8192
#define Dn 64
#define CTXn 256
#define Hn 512
#define Rn 8

#define WQ_SZ  (64 * 512 * 12)   // 393216
#define WOQ_SZ (64 * 64 * 20)    //  81920
#define WCP_SZ (CTXn * Hn)       // 131072

// lgkm-only barrier: drains LDS ops for cross-wave visibility, leaves global
// loads in flight. Memory-clobber asm pins memory-op ordering.
#define BARRIER() do {                                      \
    asm volatile("s_waitcnt lgkmcnt(0)" ::: "memory");      \
    __builtin_amdgcn_s_barrier();                           \
    asm volatile("" ::: "memory");                          \
  } while (0)

// sorted index p -> original hidden unit h, and its degree k.
__device__ __forceinline__ int perm_of(int p, int* degout) {
  int k, t;
  if (p < 72) { k = p / 9 + 1; t = p - (k - 1) * 9; }
  else        { int pp = p - 72; k = pp / 8 + 9; t = pp - (k - 9) * 8; }
  *degout = k;
  return (k - 1) + 63 * t;
}
// original unit h -> sorted index q.
__device__ __forceinline__ int inv_perm(int h) {
  int i = h % 63;            // = degree-1
  int t = h / 63;
  int base = (i < 9) ? 9 * i : 72 + 8 * (i - 8);   // S_of(i+1)
  return base + t;
}

// ---------------- prep: scan-order, coalesced reads -------------------------
// R0 W2-scan:  W2[hq][hp], hp=63e+i -> Wq[i][qs(hq)][e]
// R1 W1-scan:  W1[hq][i]            -> Wq[i][qs(hq)][9]
// R2 Wo-scan:  Wo[o][hp], hp=63p+i  -> Woq[i][o&63][(o>>6)*10+p]
// R3 Wc-scan:  Wc[hq][cc]           -> WcpT[cc][qs(hq)]   (plain layout: main
//              kernel thread t owns unit q=t, reads WcpT[cc*512+t] coalesced)
// R4 zero:     Wq[i>=8][q][8], Woq[i>=8][j][8|18]  (9-wide loop pads)
// R5 biases:   b1p/b2p (512 each, scattered reads, negligible)
#define R0e 262144
#define R1e (R0e + 32768)
#define R2e (R1e + 65536)
#define R3e (R2e + 131072)
#define R4e (R3e + 35840)
#define R5e (R4e + 1024)
__global__ void prep_kernel(const float* __restrict__ W1, const float* __restrict__ Wc,
                            const float* __restrict__ W2, const float* __restrict__ Wo,
                            const float* __restrict__ b1, const float* __restrict__ b2,
                            float* __restrict__ Wq, float* __restrict__ Woq,
                            float* __restrict__ WcpT, float* __restrict__ b1p,
                            float* __restrict__ b2p) {
  int idx = blockIdx.x * 256 + threadIdx.x;
  if (idx < R0e) {                      // W2 scan (coalesced read)
    int hq = idx >> 9, hp = idx & 511;
    int i = hp % 63, e = hp / 63;       // group i, slot e (< c by construction)
    Wq[i * 6144 + inv_perm(hq) * 12 + e] = W2[idx];
  } else if (idx < R1e) {               // W1 scan
    int jj = idx - R0e;
    int hq = jj >> 6, i = jj & 63;
    Wq[i * 6144 + inv_perm(hq) * 12 + 9] = W1[jj];
  } else if (idx < R2e) {               // Wo scan
    int jj = idx - R1e;
    int o = jj >> 9, hp = jj & 511;
    int i = hp % 63, p = hp / 63;
    int j = o & 63, half = o >> 6;
    Woq[i * 1280 + j * 20 + half * 10 + p] = Wo[jj];
  } else if (idx < R3e) {               // Wc scan (plain sorted layout)
    int jj = idx - R2e;
    int hq = jj >> 8, cc = jj & 255;
    WcpT[cc * 512 + inv_perm(hq)] = Wc[jj];
  } else if (idx < R4e) {               // zero the 9th slots for 8-wide groups
    int z = idx - R3e;
    if (z < 28672) {                    // Wq[i][q][8], i = 8..63
      int i = 8 + (z >> 9), q = z & 511;
      Wq[i * 6144 + q * 12 + 8] = 0.f;
    } else {                            // Woq[i][j][8 or 18], i = 8..63
      int z2 = z - 28672;
      int i = 8 + (z2 >> 7), r = z2 & 127;
      int j = r & 63, half = r >> 6;
      Woq[i * 1280 + j * 20 + half * 10 + 8] = 0.f;
    }
  } else if (idx < R5e) {               // permuted biases
    int z = idx - R4e;
    if (z < 512) {
      int dq; int hq = perm_of(z, &dq);
      b1p[z] = b1[hq];
    } else {
      int q = z - 512;
      int dq; int hq = perm_of(q, &dq);
      b2p[q] = b2[hq];
    }
  }
}

// ---------------- main fused kernel ------------------------------------------
// 512 threads: thread t = (wave rp = t>>6, col l = t&63), owns sorted unit q=t.
// Wave rp owns output row rp (8 rows/block). 1024 blocks, 4/CU, 32 waves/CU.
__global__ __launch_bounds__(512, 8)
void made_pk_kernel(
    const float* __restrict__ context, const float* __restrict__ WcpT,
    const float* __restrict__ b1p,
    const float* __restrict__ Wq, const float* __restrict__ Woq,
    const float* __restrict__ b2p, const float* __restrict__ bo,
    const float* __restrict__ eps, float* __restrict__ out) {
  __shared__ __align__(16) float ctxT[CTXn][8];   // transposed: [cc][row]
  __shared__ __align__(16) float zcur[8];         // z_i per row
  __shared__ __align__(16) float h1g[9][8];       // group-i h1: [slot][row]
  __shared__ __align__(16) float h2g[8][12];      // group-i h2: [row][slot] pad

  int t = threadIdx.x;
  int b0 = blockIdx.x * Rn;
  int rp = t >> 6, l = t & 63;
  int q = t;                              // owned sorted unit

  int g = ((q < 72) ? q / 9 + 1 : (q - 72) / 8 + 9) - 1;   // finalize step
  int qm = q | 63;                        // wave-uniform max unit
  int gms = __builtin_amdgcn_readfirstlane(
      ((qm < 72) ? qm / 9 + 1 : (qm - 72) / 8 + 9) - 1);

  // ---- stage ctx transposed: coalesced global read, strided LDS write ----
  #pragma unroll
  for (int j = 0; j < 4; ++j) {
    int idx = t + 512 * j;
    int r = idx >> 8, cc = idx & 255;
    ctxT[cc][r] = context[(b0 + r) * CTXn + cc];
  }
  BARRIER();

  // ---- ctx GEMM: a1[r2] = rows (2r2,2r2+1) preact for unit q ----
  f2 a1[4];
  {
    float bias = b1p[q];
    #pragma unroll
    for (int r2 = 0; r2 < 4; ++r2) a1[r2] = (f2){bias, bias};
  }
  {
    const float* wc = WcpT + q;
    #pragma clang loop unroll_count(4)
    for (int cc = 0; cc < CTXn; ++cc) {
      float w = wc[cc * Hn];              // coalesced across wave
      float4 xa = *(const float4*)&ctxT[cc][0];   // rows 0-3 (broadcast)
      float4 xb = *(const float4*)&ctxT[cc][4];   // rows 4-7
      f2 wv = (f2){w, w};
      a1[0] += wv * (f2){xa.x, xa.y};
      a1[1] += wv * (f2){xa.z, xa.w};
      a1[2] += wv * (f2){xb.x, xb.y};
      a1[3] += wv * (f2){xb.z, xb.w};
    }
  }

  f2 a2[4];
  {
    float bb = b2p[q];
    #pragma unroll
    for (int r2 = 0; r2 < 4; ++r2) a2[r2] = (f2){bb, bb};
  }

  float ocA = bo[l], ocB = bo[l + 64];    // output col l, row rp
  float ez = eps[(b0 + rp) * Dn + l];
  float zs = 0.f, mus = 0.f, scs = 0.f;

  const float* wqp = Wq + (size_t)q * 12;
  const float* wop = Woq + (size_t)l * 20;

  // ---- sequential loop: 3 raw barriers/step (must stay rolled) ----
  #pragma clang loop unroll(disable)
  for (int i = 0; i < Dn; ++i) {
    // E: thread (rp, l==i) finalizes col i for row rp (oacc through D(i-1))
    if (l == i) {
      float pre = ocB;
      float sc = fmaxf(pre, 0.f) + __logf(1.f + __expf(-fabsf(pre)));
      float z = ocA + sc * ez;
      zcur[rp] = z;
      zs = z; mus = ocA; scs = sc;
    }
    bool live = (i <= gms);                        // wave-uniform
    float4 c2;
    if (live) c2 = *(const float4*)(wqp + 8);      // slots 8-11; latency hides
    BARRIER();                                     // bar1: z published

    int sb = (i < 8) ? 9 * i : 8 * i + 8;          // group-i base
    float4 c0, c1;
    if (live) {
      c0 = *(const float4*)wqp;                    // slots 0-3 (for MID)
      c1 = *(const float4*)(wqp + 4);              // slots 4-7
      float4 za = *(const float4*)&zcur[0];
      float4 zb = *(const float4*)&zcur[4];
      // FA: a1 += z_i * W1 (slot 9 = c2.y); publish h1 if finalizing
      f2 wv = (f2){c2.y, c2.y};
      a1[0] += wv * (f2){za.x, za.y};
      a1[1] += wv * (f2){za.z, za.w};
      a1[2] += wv * (f2){zb.x, zb.y};
      a1[3] += wv * (f2){zb.z, zb.w};
      if (g == i) {
        int pp = q - sb;
        float4 h0 = {fmaxf(a1[0].x, 0.f), fmaxf(a1[0].y, 0.f),
                     fmaxf(a1[1].x, 0.f), fmaxf(a1[1].y, 0.f)};
        float4 h1_ = {fmaxf(a1[2].x, 0.f), fmaxf(a1[2].y, 0.f),
                      fmaxf(a1[3].x, 0.f), fmaxf(a1[3].y, 0.f)};
        *(float4*)&h1g[pp][0] = h0; *(float4*)&h1g[pp][4] = h1_;
      }
    }
    BARRIER();                                     // bar2: h1 published

    if (live) {
      // MID: a2 += h1(group i) . W2 slots 0..8 (slot 8 zeroed in prep, i>=8)
      float wA[9] = {c0.x, c0.y, c0.z, c0.w, c1.x, c1.y, c1.z, c1.w, c2.x};
      #pragma unroll
      for (int p = 0; p < 9; ++p) {
        float4 ha = *(const float4*)&h1g[p][0];    // broadcast
        float4 hb = *(const float4*)&h1g[p][4];
        f2 wv = (f2){wA[p], wA[p]};
        a2[0] += wv * (f2){ha.x, ha.y};
        a2[1] += wv * (f2){ha.z, ha.w};
        a2[2] += wv * (f2){hb.x, hb.y};
        a2[3] += wv * (f2){hb.z, hb.w};
      }
      if (g == i) {                                // publish h2 (row-major)
        int pp = q - sb;
        h2g[0][pp] = fmaxf(a2[0].x, 0.f);
        h2g[1][pp] = fmaxf(a2[0].y, 0.f);
        h2g[2][pp] = fmaxf(a2[1].x, 0.f);
        h2g[3][pp] = fmaxf(a2[1].y, 0.f);
        h2g[4][pp] = fmaxf(a2[2].x, 0.f);
        h2g[5][pp] = fmaxf(a2[2].y, 0.f);
        h2g[6][pp] = fmaxf(a2[3].x, 0.f);
        h2g[7][pp] = fmaxf(a2[3].y, 0.f);
      }
    }
    BARRIER();                                     // bar3: h2 published

    // D: oacc += h2(group i, row rp) . Wo cols (l, l+64); slot-8 weight
    // zeroed in prep for i>=8 so stale h2g[rp][8] contributes nothing.
    {
      const float4* w4 = (const float4*)wop;
      float4 B0 = w4[0], B1 = w4[1], B2_ = w4[2], B3 = w4[3], B4 = w4[4];
      float4 hA = *(const float4*)&h2g[rp][0];     // wave-uniform addr
      float4 hB = *(const float4*)&h2g[rp][4];
      float h8 = h2g[rp][8];
      float wBa[9] = {B0.x, B0.y, B0.z, B0.w, B1.x, B1.y, B1.z, B1.w, B2_.x};
      float wBb[9] = {B2_.z, B2_.w, B3.x, B3.y, B3.z, B3.w, B4.x, B4.y, B4.z};
      float hv[9] = {hA.x, hA.y, hA.z, hA.w, hB.x, hB.y, hB.z, hB.w, h8};
      #pragma unroll
      for (int p = 0; p < 9; ++p) {
        ocA = fmaf(wBa[p], hv[p], ocA);
        ocB = fmaf(wBb[p], hv[p], ocB);
      }
    }
    wqp += 6144; wop += 1280;
  }

  // ---- epilogue: thread (rp, l) holds z/mu/sc for row rp, col l ----
  out[(b0 + rp) * Dn + l] = zs;
  out[Bn * Dn + (b0 + rp) * Dn + l] = mus;
  out[2 * Bn * Dn + (b0 + rp) * Dn + l] = scs;
}

extern "C" void kernel_launch(void* const* d_in, const int* in_sizes, int n_in,
                              void* d_out, int out_size, void* d_ws, size_t ws_size,
                              hipStream_t stream) {
  const float* context = (const float*)d_in[0];
  const float* eps     = (const float*)d_in[1];
  const float* W1      = (const float*)d_in[2];
  const float* b1      = (const float*)d_in[3];
  const float* Wc      = (const float*)d_in[4];
  const float* W2      = (const float*)d_in[5];
  const float* b2      = (const float*)d_in[6];
  const float* Wo      = (const float*)d_in[7];
  const float* bo      = (const float*)d_in[8];
  float* out = (float*)d_out;

  float* ws   = (float*)d_ws;
  float* Wq   = ws;                        // 393216 floats
  float* Woq  = Wq + WQ_SZ;                //  81920
  float* WcpT = Woq + WOQ_SZ;              // 131072
  float* b1p  = WcpT + WCP_SZ;             //    512
  float* b2p  = b1p + 512;                 //    512
  // total ws use: ~2.4 MB (L2-resident)

  prep_kernel<<<(R5e + 255) / 256, 256, 0, stream>>>(
      W1, Wc, W2, Wo, b1, b2, Wq, Woq, WcpT, b1p, b2p);
  made_pk_kernel<<<Bn / Rn, 512, 0, stream>>>(context, WcpT, b1p, Wq, Woq,
                                              b2p, bo, eps, out);
}

// Round 6
// 237.237 us; speedup vs baseline: 1.5096x; 1.5096x over previous
//
#include <hip/hip_runtime.h>
#include <math.h>

// MADE autoregressive sampler, incremental-by-degree, v16 (resubmit #2).
// B=8192, D=64, CTX=256, H=512. Units sorted by degree (mh = h%63+1).
// Rounds 4+5 died with infra-level "container failed twice" and NO timing
// JSON (no acquire/pytest phases) => container provisioning failure, not a
// kernel verdict. Kernel audited twice: barriers unconditional + uniform trip
// count (no ring-hang vector), all accesses in bounds, VGPR ~170-200 < 256
// cap, LDS 18.1KB. Theory untested; resubmitting.
// v16: amortization attack. Evidence: v14 (4w blocks, Rn=8) 185us @ VALU 44.6;
// v15 (8w blocks, Rn=8) 310us @ VALU 29.7 + occ 77 => wave count is NOT the
// lever; per-CU L2 weight re-read (45KB/step per 8-row pipeline => ~85us floor
// at Rn=8) + barrier-phase bubbles are. Fix: Rn=16 with the SAME 256-thread /
// 4-wave / 2-unit-per-thread structure as v14: every loaded weight now feeds
// 16 rows (halves per-CU L2 weight traffic, doubles fma per phase to fill
// bubbles), barriers stay 4-wave. Grid 512 = 2 blocks/CU (grid-limited
// occupancy ~25% is EXPECTED). Spill tripwire = WRITE_SIZE (stay 10240 KB).
// Kept from v14: raw lgkm-only barriers, pk-packed ctx GEMM with
// pair-interleaved WcpT, Woq prefetch between bar2/bar3.

typedef float f2 __attribute__((ext_vector_type(2)));

#define Bn 8192
#define Dn 64
#define CTXn 256
#define Hn 512
#define Rn 16

#define WQ_SZ  (64 * 512 * 12)   // 393216
#define WOQ_SZ (64 * 64 * 20)    //  81920
#define WCP_SZ (CTXn * Hn)       // 131072

// lgkm-only barrier: drains LDS ops for cross-wave visibility, leaves global
// loads in flight. Memory-clobber asm pins memory-op ordering.
#define BARRIER() do {                                      \
    asm volatile("s_waitcnt lgkmcnt(0)" ::: "memory");      \
    __builtin_amdgcn_s_barrier();                           \
    asm volatile("" ::: "memory");                          \
  } while (0)

// sorted index p -> original hidden unit h, and its degree k.
__device__ __forceinline__ int perm_of(int p, int* degout) {
  int k, t;
  if (p < 72) { k = p / 9 + 1; t = p - (k - 1) * 9; }
  else        { int pp = p - 72; k = pp / 8 + 9; t = pp - (k - 9) * 8; }
  *degout = k;
  return (k - 1) + 63 * t;
}
// original unit h -> sorted index q.
__device__ __forceinline__ int inv_perm(int h) {
  int i = h % 63;            // = degree-1
  int t = h / 63;
  int base = (i < 9) ? 9 * i : 72 + 8 * (i - 8);   // S_of(i+1)
  return base + t;
}

// ---------------- prep: scan-order, coalesced reads (unchanged) -------------
#define R0e 262144
#define R1e (R0e + 32768)
#define R2e (R1e + 65536)
#define R3e (R2e + 131072)
#define R4e (R3e + 35840)
#define R5e (R4e + 1024)
__global__ void prep_kernel(const float* __restrict__ W1, const float* __restrict__ Wc,
                            const float* __restrict__ W2, const float* __restrict__ Wo,
                            const float* __restrict__ b1, const float* __restrict__ b2,
                            float* __restrict__ Wq, float* __restrict__ Woq,
                            float* __restrict__ WcpT, float* __restrict__ b1p,
                            float* __restrict__ b2p) {
  int idx = blockIdx.x * 256 + threadIdx.x;
  if (idx < R0e) {                      // W2 scan (coalesced read)
    int hq = idx >> 9, hp = idx & 511;
    int i = hp % 63, e = hp / 63;
    Wq[i * 6144 + inv_perm(hq) * 12 + e] = W2[idx];
  } else if (idx < R1e) {               // W1 scan
    int jj = idx - R0e;
    int hq = jj >> 6, i = jj & 63;
    Wq[i * 6144 + inv_perm(hq) * 12 + 9] = W1[jj];
  } else if (idx < R2e) {               // Wo scan
    int jj = idx - R1e;
    int o = jj >> 9, hp = jj & 511;
    int i = hp % 63, p = hp / 63;
    int j = o & 63, half = o >> 6;
    Woq[i * 1280 + j * 20 + half * 10 + p] = Wo[jj];
  } else if (idx < R3e) {               // Wc scan (pair-interleaved layout)
    int jj = idx - R2e;
    int hq = jj >> 8, cc = jj & 255;
    int p = inv_perm(hq);
    int slot = (p < 256) ? (2 * p) : (2 * (p - 256) + 1);
    WcpT[cc * 512 + slot] = Wc[jj];
  } else if (idx < R4e) {               // zero the 9th slots for 8-wide groups
    int z = idx - R3e;
    if (z < 28672) {                    // Wq[i][q][8], i = 8..63
      int i = 8 + (z >> 9), q = z & 511;
      Wq[i * 6144 + q * 12 + 8] = 0.f;
    } else {                            // Woq[i][j][8 or 18], i = 8..63
      int z2 = z - 28672;
      int i = 8 + (z2 >> 7), r = z2 & 127;
      int j = r & 63, half = r >> 6;
      Woq[i * 1280 + j * 20 + half * 10 + 8] = 0.f;
    }
  } else if (idx < R5e) {               // permuted biases
    int z = idx - R4e;
    if (z < 512) {
      int dq; int hq = perm_of(z, &dq);
      b1p[z] = b1[hq];
    } else {
      int q = z - 512;
      int dq; int hq = perm_of(q, &dq);
      b2p[q] = b2[hq];
    }
  }
}

// ---------------- main fused kernel ------------------------------------------
// 256 threads = 4 waves; wave rp owns rows 4rp..4rp+3; thread (rp,l) owns
// units q0=t, q1=t+256 and output cols (l, l+64) of its wave's 4 rows.
__global__ __launch_bounds__(256, 2)
void made_pk_kernel(
    const float* __restrict__ context, const float* __restrict__ WcpT,
    const float* __restrict__ b1p,
    const float* __restrict__ Wq, const float* __restrict__ Woq,
    const float* __restrict__ b2p, const float* __restrict__ bo,
    const float* __restrict__ eps, float* __restrict__ out) {
  __shared__ __align__(16) float ctxR[Rn][264];
  __shared__ __align__(16) float zcur[16];
  __shared__ __align__(16) float h1g[9][16];
  __shared__ __align__(16) float h2g[9][16];

  int t = threadIdx.x;
  int b0 = blockIdx.x * Rn;
  int rp = t >> 6, l = t & 63;
  int q0 = t, q1 = t + 256;              // owned sorted units

  int g0 = ((q0 < 72) ? q0 / 9 + 1 : (q0 - 72) / 8 + 9) - 1;   // finalize steps
  int g1 = ((q1 - 72) / 8 + 9) - 1;
  int qm = t | 63;                        // wave-uniform max index
  int gm0s = __builtin_amdgcn_readfirstlane(
      ((qm < 72) ? qm / 9 + 1 : (qm - 72) / 8 + 9) - 1);
  int gm1s = __builtin_amdgcn_readfirstlane(((qm + 256 - 72) / 8 + 9) - 1);

  // ---- stage ctx (16 rows) ----
  #pragma unroll
  for (int r = 0; r < Rn; ++r)
    ctxR[r][t] = context[(b0 + r) * CTXn + t];
  BARRIER();

  // ---- ctx GEMM, unit-pair packed: accu[r] = (q0 acc, q1 acc) for row r ----
  f2 accu[16];
  {
    f2 bias = (f2){b1p[q0], b1p[q1]};
    #pragma unroll
    for (int r = 0; r < 16; ++r) accu[r] = bias;
  }
  {
    const float* wc = WcpT + 2 * t;      // pair base for this thread
    #pragma clang loop unroll(disable)
    for (int c4 = 0; c4 < CTXn / 4; ++c4) {
      f2 wv0 = *(const f2*)&wc[0];
      f2 wv1 = *(const f2*)&wc[Hn];
      f2 wv2 = *(const f2*)&wc[2 * Hn];
      f2 wv3 = *(const f2*)&wc[3 * Hn];
      wc += 4 * Hn;
      #pragma unroll
      for (int hf = 0; hf < 2; ++hf) {   // row halves: 0-7, 8-15
        float4 x[8];
        #pragma unroll
        for (int r = 0; r < 8; ++r) x[r] = *(const float4*)&ctxR[8 * hf + r][4 * c4];
        #pragma unroll
        for (int r = 0; r < 8; ++r) {
          accu[8 * hf + r] += (f2){x[r].x, x[r].x} * wv0;
          accu[8 * hf + r] += (f2){x[r].y, x[r].y} * wv1;
          accu[8 * hf + r] += (f2){x[r].z, x[r].z} * wv2;
          accu[8 * hf + r] += (f2){x[r].w, x[r].w} * wv3;
        }
      }
    }
  }

  // ---- unpack into per-unit row-pair accumulators (8 f2 = 16 rows each) ----
  f2 a10[8], a11[8], a20[8], a21[8];
  #pragma unroll
  for (int r2 = 0; r2 < 8; ++r2) {
    a10[r2] = (f2){accu[2 * r2].x, accu[2 * r2 + 1].x};
    a11[r2] = (f2){accu[2 * r2].y, accu[2 * r2 + 1].y};
  }
  {
    float bb0 = b2p[q0], bb1 = b2p[q1];
    #pragma unroll
    for (int r2 = 0; r2 < 8; ++r2) {
      a20[r2] = (f2){bb0, bb0};
      a21[r2] = (f2){bb1, bb1};
    }
  }

  // output state: cols (l, l+64) x rows 4rp..4rp+3
  f2 ocA[2], ocB[2];
  ocA[0] = ocA[1] = (f2){bo[l], bo[l]};
  ocB[0] = ocB[1] = (f2){bo[l + 64], bo[l + 64]};
  int r0 = b0 + 4 * rp;
  f2 ez01 = (f2){eps[(r0 + 0) * Dn + l], eps[(r0 + 1) * Dn + l]};
  f2 ez23 = (f2){eps[(r0 + 2) * Dn + l], eps[(r0 + 3) * Dn + l]};
  f2 zs01 = (f2){0.f, 0.f}, zs23 = zs01;
  f2 mus01 = zs01, mus23 = zs01, scs01 = zs01, scs23 = zs01;

  const float* wq0p = Wq + (size_t)q0 * 12;
  const float* wq1p = Wq + (size_t)q1 * 12;
  const float* wopp = Woq + (size_t)l * 20;

  // ---- sequential loop: 3 raw barriers/step (must stay rolled) ----
  #pragma clang loop unroll(disable)
  for (int i = 0; i < Dn; ++i) {
    // E: thread (rp, l==i) finalizes cols (i, i+64) for its wave's 4 rows
    if (l == i) {
      f2 p01 = ocB[0], p23 = ocB[1];
      float s0 = fmaxf(p01.x, 0.f) + __logf(1.f + __expf(-fabsf(p01.x)));
      float s1 = fmaxf(p01.y, 0.f) + __logf(1.f + __expf(-fabsf(p01.y)));
      float s2 = fmaxf(p23.x, 0.f) + __logf(1.f + __expf(-fabsf(p23.x)));
      float s3 = fmaxf(p23.y, 0.f) + __logf(1.f + __expf(-fabsf(p23.y)));
      f2 sc01 = (f2){s0, s1}, sc23 = (f2){s2, s3};
      f2 z01 = ocA[0] + sc01 * ez01;
      f2 z23 = ocA[1] + sc23 * ez23;
      float4 zq = {z01.x, z01.y, z23.x, z23.y};
      *(float4*)&zcur[4 * rp] = zq;
      zs01 = z01; zs23 = z23;
      mus01 = ocA[0]; mus23 = ocA[1];
      scs01 = sc01; scs23 = sc23;
    }
    BARRIER();                                     // bar1: z published

    int sb = (i < 8) ? 9 * i : 8 * i + 8;          // group-i base
    bool liveB = (i <= gm1s);                      // wave-uniform
    bool liveA = (i <= gm0s);
    float4 A1c0, A1c1, A1c2, A0c0, A0c1, A0c2;
    if (liveB) {
      const float4* a4 = (const float4*)wq1p;      // 3 b128, imm offsets
      A1c0 = a4[0]; A1c1 = a4[1]; A1c2 = a4[2];
      if (liveA) {
        const float4* b4 = (const float4*)wq0p;
        A0c0 = b4[0]; A0c1 = b4[1]; A0c2 = b4[2];
      }
      float4 za = *(const float4*)&zcur[0];
      float4 zb = *(const float4*)&zcur[4];
      float4 zc = *(const float4*)&zcur[8];
      float4 zd = *(const float4*)&zcur[12];
      f2 zz[8] = {(f2){za.x, za.y}, (f2){za.z, za.w},
                  (f2){zb.x, zb.y}, (f2){zb.z, zb.w},
                  (f2){zc.x, zc.y}, (f2){zc.z, zc.w},
                  (f2){zd.x, zd.y}, (f2){zd.z, zd.w}};
      // FA unit1: a1 += z_i * W1 (slot [9] = chunk2.y); publish if finalizing
      {
        f2 wv = (f2){A1c2.y, A1c2.y};
        #pragma unroll
        for (int r2 = 0; r2 < 8; ++r2) a11[r2] += wv * zz[r2];
        if (g1 == i) {
          int pp = q1 - sb;
          #pragma unroll
          for (int s = 0; s < 4; ++s) {
            float4 h = {fmaxf(a11[2 * s].x, 0.f), fmaxf(a11[2 * s].y, 0.f),
                        fmaxf(a11[2 * s + 1].x, 0.f), fmaxf(a11[2 * s + 1].y, 0.f)};
            *(float4*)&h1g[pp][4 * s] = h;
          }
        }
      }
      if (liveA) {
        f2 wv = (f2){A0c2.y, A0c2.y};
        #pragma unroll
        for (int r2 = 0; r2 < 8; ++r2) a10[r2] += wv * zz[r2];
        if (g0 == i) {
          int pp = q0 - sb;
          #pragma unroll
          for (int s = 0; s < 4; ++s) {
            float4 h = {fmaxf(a10[2 * s].x, 0.f), fmaxf(a10[2 * s].y, 0.f),
                        fmaxf(a10[2 * s + 1].x, 0.f), fmaxf(a10[2 * s + 1].y, 0.f)};
            *(float4*)&h1g[pp][4 * s] = h;
          }
        }
      }
    }
    BARRIER();                                     // bar2: h1 published

    // Woq prefetch (used in D after bar3; no vmcnt drain at barriers, so it
    // stays in flight across bar3 and MID hides its latency)
    const float4* w4 = (const float4*)wopp;
    float4 B0 = w4[0], B1 = w4[1], B2_ = w4[2], B3 = w4[3], B4 = w4[4];

    if (liveB) {
      float wA1[9] = {A1c0.x, A1c0.y, A1c0.z, A1c0.w,
                      A1c1.x, A1c1.y, A1c1.z, A1c1.w, A1c2.x};
      if (liveA) {
        float wA0[9] = {A0c0.x, A0c0.y, A0c0.z, A0c0.w,
                        A0c1.x, A0c1.y, A0c1.z, A0c1.w, A0c2.x};
        #pragma unroll
        for (int p = 0; p < 9; ++p) {
          float4 ha = *(const float4*)&h1g[p][0];
          float4 hb = *(const float4*)&h1g[p][4];
          float4 hc = *(const float4*)&h1g[p][8];
          float4 hd = *(const float4*)&h1g[p][12];
          f2 h[8] = {(f2){ha.x, ha.y}, (f2){ha.z, ha.w},
                     (f2){hb.x, hb.y}, (f2){hb.z, hb.w},
                     (f2){hc.x, hc.y}, (f2){hc.z, hc.w},
                     (f2){hd.x, hd.y}, (f2){hd.z, hd.w}};
          f2 wv1 = (f2){wA1[p], wA1[p]};
          f2 wv0 = (f2){wA0[p], wA0[p]};
          #pragma unroll
          for (int r2 = 0; r2 < 8; ++r2) {
            a21[r2] += wv1 * h[r2];
            a20[r2] += wv0 * h[r2];
          }
        }
      } else {
        #pragma unroll
        for (int p = 0; p < 9; ++p) {
          float4 ha = *(const float4*)&h1g[p][0];
          float4 hb = *(const float4*)&h1g[p][4];
          float4 hc = *(const float4*)&h1g[p][8];
          float4 hd = *(const float4*)&h1g[p][12];
          f2 h[8] = {(f2){ha.x, ha.y}, (f2){ha.z, ha.w},
                     (f2){hb.x, hb.y}, (f2){hb.z, hb.w},
                     (f2){hc.x, hc.y}, (f2){hc.z, hc.w},
                     (f2){hd.x, hd.y}, (f2){hd.z, hd.w}};
          f2 wv1 = (f2){wA1[p], wA1[p]};
          #pragma unroll
          for (int r2 = 0; r2 < 8; ++r2) a21[r2] += wv1 * h[r2];
        }
      }
      if (g1 == i) {
        int pp = q1 - sb;
        #pragma unroll
        for (int s = 0; s < 4; ++s) {
          float4 h = {fmaxf(a21[2 * s].x, 0.f), fmaxf(a21[2 * s].y, 0.f),
                      fmaxf(a21[2 * s + 1].x, 0.f), fmaxf(a21[2 * s + 1].y, 0.f)};
          *(float4*)&h2g[pp][4 * s] = h;
        }
      }
      if (liveA && g0 == i) {
        int pp = q0 - sb;
        #pragma unroll
        for (int s = 0; s < 4; ++s) {
          float4 h = {fmaxf(a20[2 * s].x, 0.f), fmaxf(a20[2 * s].y, 0.f),
                      fmaxf(a20[2 * s + 1].x, 0.f), fmaxf(a20[2 * s + 1].y, 0.f)};
          *(float4*)&h2g[pp][4 * s] = h;
        }
      }
    }
    BARRIER();                                     // bar3: h2 published

    // D: oacc += h2(group i) . Wo cols (l, l+64), rows 4rp..4rp+3.
    // Slot-8 weight zeroed in prep for i>=8 -> stale h2g[8][*] harmless.
    {
      float wBa[9] = {B0.x, B0.y, B0.z, B0.w, B1.x, B1.y, B1.z, B1.w, B2_.x};
      float wBb[9] = {B2_.z, B2_.w, B3.x, B3.y, B3.z, B3.w, B4.x, B4.y, B4.z};
      #pragma unroll
      for (int p = 0; p < 9; ++p) {
        float4 hq = *(const float4*)&h2g[p][4 * rp];   // wave-uniform addr
        f2 h01 = (f2){hq.x, hq.y}, h23 = (f2){hq.z, hq.w};
        f2 wa = (f2){wBa[p], wBa[p]}, wb = (f2){wBb[p], wBb[p]};
        ocA[0] += wa * h01; ocA[1] += wa * h23;
        ocB[0] += wb * h01; ocB[1] += wb * h23;
      }
    }
    wq0p += 6144; wq1p += 6144; wopp += 1280;
  }

  // ---- epilogue: thread (rp, l) holds z/mu/sc for rows 4rp..4rp+3, col l ----
  out[(r0 + 0) * Dn + l] = zs01.x;
  out[(r0 + 1) * Dn + l] = zs01.y;
  out[(r0 + 2) * Dn + l] = zs23.x;
  out[(r0 + 3) * Dn + l] = zs23.y;
  out[Bn * Dn + (r0 + 0) * Dn + l] = mus01.x;
  out[Bn * Dn + (r0 + 1) * Dn + l] = mus01.y;
  out[Bn * Dn + (r0 + 2) * Dn + l] = mus23.x;
  out[Bn * Dn + (r0 + 3) * Dn + l] = mus23.y;
  out[2 * Bn * Dn + (r0 + 0) * Dn + l] = scs01.x;
  out[2 * Bn * Dn + (r0 + 1) * Dn + l] = scs01.y;
  out[2 * Bn * Dn + (r0 + 2) * Dn + l] = scs23.x;
  out[2 * Bn * Dn + (r0 + 3) * Dn + l] = scs23.y;
}

extern "C" void kernel_launch(void* const* d_in, const int* in_sizes, int n_in,
                              void* d_out, int out_size, void* d_ws, size_t ws_size,
                              hipStream_t stream) {
  const float* context = (const float*)d_in[0];
  const float* eps     = (const float*)d_in[1];
  const float* W1      = (const float*)d_in[2];
  const float* b1      = (const float*)d_in[3];
  const float* Wc      = (const float*)d_in[4];
  const float* W2      = (const float*)d_in[5];
  const float* b2      = (const float*)d_in[6];
  const float* Wo      = (const float*)d_in[7];
  const float* bo      = (const float*)d_in[8];
  float* out = (float*)d_out;

  float* ws   = (float*)d_ws;
  float* Wq   = ws;                        // 393216 floats
  float* Woq  = Wq + WQ_SZ;                //  81920
  float* WcpT = Woq + WOQ_SZ;              // 131072
  float* b1p  = WcpT + WCP_SZ;             //    512
  float* b2p  = b1p + 512;                 //    512
  // total ws use: ~2.4 MB (L2-resident)

  prep_kernel<<<(R5e + 255) / 256, 256, 0, stream>>>(
      W1, Wc, W2, Wo, b1, b2, Wq, Woq, WcpT, b1p, b2p);
  made_pk_kernel<<<Bn / Rn, 256, 0, stream>>>(context, WcpT, b1p, Wq, Woq,
                                              b2p, bo, eps, out);
}